// Round 11
// baseline (743.680 us; speedup 1.0000x reference)
//
#include <hip/hip_runtime.h>
#include <math.h>

#define Bn 256
#define Cn 3
#define Hn 224
#define Wn 224
#define CROPD 190

static constexpr int PLANE = Hn * Wn;   // 50176

#define TILE 32
// F (source) tile, f32, ZERO-PADDED outside image (unclamped bbox)
#define FH 72
#define FSTR 76
// P tile, f32, zero-padded (unclamped rot bbox)
#define PHR 44
#define PSTR 52
// R/T tiles overlay F region
#define RSTR 36

#define NWG (Bn * 49)            // 12,544 blocks: one per (batch,tile), 3 channels each
#define CHUNK (NWG / 8)          // 1568

__device__ int    g_i0[Wn];
__device__ float4 g_wt[Wn];

__device__ __forceinline__ float keys_cubic(float x) {
    if (x < 1.f) return ((1.5f * x - 2.5f) * x) * x + 1.f;
    if (x < 2.f) return ((-0.5f * x + 2.5f) * x - 4.f) * x + 2.f;
    return 0.f;
}
__device__ __forceinline__ float rflf(float v) {
    return __int_as_float(__builtin_amdgcn_readfirstlane(__float_as_int(v)));
}
__device__ __forceinline__ int rfli(int v) { return __builtin_amdgcn_readfirstlane(v); }
__device__ __forceinline__ int swz_block(int bid) {
    return (bid & 7) * CHUNK + (bid >> 3);   // bijective, NWG%8==0
}

// params[b*12 + {0..7: homography, 8: cos, 9: sin, 10: brightness, 11: flip}]
__global__ void params_kernel(const int* __restrict__ ep_raw,
                              const int* __restrict__ angles,
                              const float* __restrict__ brightness,
                              const int* __restrict__ flip_mask,
                              float* __restrict__ params) {
    int b = threadIdx.x;

    if (b < Wn) {
        float sf = ((float)b + 0.5f) * ((float)CROPD / (float)Wn) - 0.5f;
        int i0 = (int)floorf(sf);
        float w[4]; float s = 0.f;
#pragma unroll
        for (int k = 0; k < 4; k++) {
            int idx = i0 - 1 + k;
            float wk = (idx >= 0 && idx < CROPD) ? keys_cubic(fabsf(sf - (float)idx)) : 0.f;
            w[k] = wk; s += wk;
        }
        float inv = 1.f / s;
        g_i0[b] = i0;
        g_wt[b] = make_float4(w[0] * inv, w[1] * inv, w[2] * inv, w[3] * inv);
    }

    if (b >= Bn) return;

    const double offx[4] = {0.0, 195.0, 195.0, 0.0};
    const double offy[4] = {0.0, 0.0, 195.0, 195.0};
    const double sxc[4]  = {0.0, 223.0, 223.0, 0.0};
    const double syc[4]  = {0.0, 0.0, 223.0, 223.0};
    double M[8][9];
    for (int i = 0; i < 4; i++) {
        double ex = (double)ep_raw[b * 8 + i * 2 + 0] + offx[i];
        double ey = (double)ep_raw[b * 8 + i * 2 + 1] + offy[i];
        double sx = sxc[i], sy = syc[i];
        M[i][0] = ex; M[i][1] = ey; M[i][2] = 1.0;
        M[i][3] = 0.0; M[i][4] = 0.0; M[i][5] = 0.0;
        M[i][6] = -sx * ex; M[i][7] = -sx * ey; M[i][8] = sx;
        M[i + 4][0] = 0.0; M[i + 4][1] = 0.0; M[i + 4][2] = 0.0;
        M[i + 4][3] = ex; M[i + 4][4] = ey; M[i + 4][5] = 1.0;
        M[i + 4][6] = -sy * ex; M[i + 4][7] = -sy * ey; M[i + 4][8] = sy;
    }
    for (int k = 0; k < 8; k++) {
        int piv = k; double best = fabs(M[k][k]);
        for (int r = k + 1; r < 8; r++) {
            double v = fabs(M[r][k]);
            if (v > best) { best = v; piv = r; }
        }
        if (piv != k)
            for (int j = 0; j < 9; j++) { double tt = M[k][j]; M[k][j] = M[piv][j]; M[piv][j] = tt; }
        double inv = 1.0 / M[k][k];
        for (int r = k + 1; r < 8; r++) {
            double f = M[r][k] * inv;
            M[r][k] = 0.0;
            for (int j = k + 1; j < 9; j++) M[r][j] -= f * M[k][j];
        }
    }
    double sol[8];
    for (int k = 7; k >= 0; k--) {
        double s = M[k][8];
        for (int j = k + 1; j < 8; j++) s -= M[k][j] * sol[j];
        sol[k] = s / M[k][k];
    }
    float* p = params + b * 12;
    for (int j = 0; j < 8; j++) p[j] = (float)sol[j];
    double th = ((double)angles[b] - 16.0) * (M_PI / 180.0);
    p[8]  = (float)cos(th);
    p[9]  = (float)sin(th);
    p[10] = 0.85f + 0.3f * brightness[b];
    p[11] = (flip_mask[b] > 0) ? 1.0f : 0.0f;
}

// Per-(batch,tile): rmeta = UNCLAMPED rot bbox (P-rect); smeta = UNCLAMPED
// persp source bbox of that P-rect (x0s aligned down to mult of 4).
__global__ void meta_kernel(const float* __restrict__ params,
                            const int* __restrict__ crop_ij,
                            int4* __restrict__ rmeta,
                            int4* __restrict__ smeta) {
    int bt = blockIdx.x * 256 + threadIdx.x;    // < 12544
    int b = bt / 49, t = bt % 49;
    int ty = (t / 7) * TILE, tx = (t % 7) * TILE;
    const float* prm = params + b * 12;

    int x0p, y0p, bwp, bhp;
    {
        float cs = prm[8], sn = prm[9];
        int ci = crop_ij[b * 2 + 0], cj = crop_ij[b * 2 + 1];
        int iymin = max(g_i0[ty] - 1, 0);
        int iymax = min(g_i0[ty + 31] + 2, CROPD - 1);
        int jmin = max(g_i0[tx] - 1, 0);
        int jmax = min(g_i0[tx + 31] + 2, CROPD - 1);
        int ry0 = iymin + ci, ry1 = iymax + ci;
        int rx0 = jmin + cj, rx1 = jmax + cj;
        const float cxc = (Wn - 1) * 0.5f;
        float minrx = 1e30f, maxrx = -1e30f, minry = 1e30f, maxry = -1e30f;
#pragma unroll
        for (int cy = 0; cy < 2; cy++) {
#pragma unroll
            for (int cxr = 0; cxr < 2; cxr++) {
                float dx = (float)(cxr ? rx1 : rx0) - cxc;
                float dy = (float)(cy ? ry1 : ry0) - cxc;
                float rx = cs * dx + sn * dy + cxc;
                float ry = -sn * dx + cs * dy + cxc;
                minrx = fminf(minrx, rx); maxrx = fmaxf(maxrx, rx);
                minry = fminf(minry, ry); maxry = fmaxf(maxry, ry);
            }
        }
        x0p = (int)floorf(minrx) - 1;
        y0p = (int)floorf(minry) - 1;
        bwp = ((int)floorf(maxrx) + 2) - x0p + 1;
        bhp = ((int)floorf(maxry) + 2) - y0p + 1;
        rmeta[bt] = make_int4(x0p, y0p, bwp, bhp);
    }

    {
        float a0 = prm[0], a1 = prm[1], a2 = prm[2];
        float a3 = prm[3], a4 = prm[4], a5 = prm[5];
        float g = prm[6], h = prm[7];
        int x1p = x0p + bwp - 1, y1p = y0p + bhp - 1;
        float minsx = 1e30f, maxsx = -1e30f, minsy = 1e30f, maxsy = -1e30f;
#pragma unroll
        for (int cy = 0; cy < 2; cy++) {
#pragma unroll
            for (int cxr = 0; cxr < 2; cxr++) {
                float Xg = (float)(cxr ? x1p : x0p) + 0.5f;
                float Yg = (float)(cy ? y1p : y0p) + 0.5f;
                float rden = 1.0f / (g * Xg + h * Yg + 1.0f);
                float sx = (a0 * Xg + a1 * Yg + a2) * rden - 0.5f;
                float sy = (a3 * Xg + a4 * Yg + a5) * rden - 0.5f;
                minsx = fminf(minsx, sx); maxsx = fmaxf(maxsx, sx);
                minsy = fminf(minsy, sy); maxsy = fmaxf(maxsy, sy);
            }
        }
        int x0s = ((int)floorf(minsx) - 1) & ~3;
        int y0s = (int)floorf(minsy) - 1;
        int bws = ((int)floorf(maxsx) + 2) - x0s + 1;
        int bhs = ((int)floorf(maxsy) + 2) - y0s + 1;
        smeta[bt] = make_int4(x0s, y0s, bws, bhs);
    }
}

// On-demand perspective sample with global taps (fallback path only).
__device__ __forceinline__ float persp_at(const float* __restrict__ xb,
                                          const float* __restrict__ nb,
                                          bool flip, float bf,
                                          float a0, float a1, float a2,
                                          float a3, float a4, float a5,
                                          float g, float h, int ixp, int iyp) {
    float Xg = (float)ixp + 0.5f, Yg = (float)iyp + 0.5f;
    float rden = __builtin_amdgcn_rcpf(g * Xg + h * Yg + 1.0f);
    float sx = (a0 * Xg + a1 * Yg + a2) * rden - 0.5f;
    float sy = (a3 * Xg + a4 * Yg + a5) * rden - 0.5f;
    float fx0 = floorf(sx), fy0 = floorf(sy);
    float wx = sx - fx0, wy = sy - fy0;
    int x0 = (int)fx0, y0 = (int)fy0;
    float acc = 0.f;
#pragma unroll
    for (int dy = 0; dy < 2; dy++) {
        int yy = y0 + dy;
        float wyv = dy ? wy : 1.f - wy;
        bool yv = (unsigned)yy < (unsigned)Hn;
        int yc = min(max(yy, 0), Hn - 1);
#pragma unroll
        for (int dx = 0; dx < 2; dx++) {
            int xx = x0 + dx;
            float wxv = dx ? wx : 1.f - wx;
            bool v = yv && ((unsigned)xx < (unsigned)Wn);
            int xc = min(max(xx, 0), Wn - 1);
            float wgt = v ? wxv * wyv : 0.f;
            int xs = flip ? (Wn - 1 - xc) : xc;
            acc += (xb[yc * Wn + xs] + 0.625f * nb[yc * Wn + xc]) * bf * wgt;
        }
    }
    return acc;
}

// One block = one (batch, 32x32 tile) x ALL 3 CHANNELS.
// Coordinate math (P/R/T/V) computed ONCE into statically-indexed registers,
// reused across the channel loop. NO launch_bounds VGPR cap (R9's (256,4)
// forced a 64-VGPR cap -> scratch spill, 5.5 GB of writes).
// LDS = 72*76*4 + 44*52*4 = 31,040 B; R/T overlay dead F region.
__global__ __launch_bounds__(256) void mega_kernel(const float* __restrict__ xin,
                                                   const float* __restrict__ noise,
                                                   const float* __restrict__ params,
                                                   const int* __restrict__ crop_ij,
                                                   const int4* __restrict__ rmeta,
                                                   const int4* __restrict__ smeta,
                                                   float* __restrict__ out) {
    __shared__ __align__(16) float smem[FH * FSTR + PHR * PSTR];
    float* Flds = smem;
    float* Plds = smem + FH * FSTR;
    float* Rlds = smem;                      // overlays F (dead after P phase)
    float* Tlds = smem + 32 * RSTR;

    int bt = swz_block(blockIdx.x);          // b*49 + t
    int b = bt / 49;
    int t = bt - b * 49;
    int ty = (t / 7) * TILE;
    int tx = (t % 7) * TILE;
    int tid = threadIdx.x;

    int4 rm = rmeta[bt];
    int x0p = rfli(rm.x), y0p = rfli(rm.y), bwp = rfli(rm.z), bhp = rfli(rm.w);
    int4 sm = smeta[bt];
    int x0s = rfli(sm.x), y0s = rfli(sm.y), bws = rfli(sm.z), bhs = rfli(sm.w);
    bool fast = (bws <= FH) && (bhs <= FH) && (bwp <= PHR) && (bhp <= PHR);

    const float* prm = params + b * 12;
    float a0 = rflf(prm[0]), a1 = rflf(prm[1]), a2 = rflf(prm[2]);
    float a3 = rflf(prm[3]), a4 = rflf(prm[4]), a5 = rflf(prm[5]);
    float g = rflf(prm[6]), h = rflf(prm[7]), bf = rflf(prm[10]);
    float cs = rflf(prm[8]), sn = rflf(prm[9]);
    bool flip = rflf(prm[11]) > 0.5f;
    int ci = rfli(crop_ij[b * 2 + 0]);
    int cj = rfli(crop_ij[b * 2 + 1]);

    int iymin = max(g_i0[ty] - 1, 0);
    int nTy = min(g_i0[ty + 31] + 2, CROPD - 1) - iymin + 1;
    int jmin = max(g_i0[tx] - 1, 0);
    int nRx = min(g_i0[tx + 31] + 2, CROPD - 1) - jmin + 1;
    int rx0 = jmin + cj, ry0 = iymin + ci;
    const float cxc = (Wn - 1) * 0.5f;

    // ---- F staging geometry (uniform) ----
    int bwq = (bws + 3) >> 2;                          // <= 18
    unsigned Mf = (1u << 20) / (unsigned)bwq + 1;
    int totF = bhs * bwq;

    // ================== channel-independent coordinate cache =================
    // P coords: 2 static elems x 4 taps. poff bit30 = out-of-image flag.
    int   psto0 = -1, psto1 = -1;
    int   poff[2][4]; float pwx[2][4], pwy[2][4];
    // R coords: 4 static elems.
    int   rsto[4], roff[4]; float rwx[4], rwy[4];
    // T coords.
    int oc = tid & 31, rbase = tid >> 5;
    float4 twt; int jc0, jc1, jc2, jc3;
    // V coords.
    float4 vwt; int iyc0, iyc1, iyc2, iyc3, voutoff;

    if (fast) {
        int bwpq = (bwp + 3) >> 2;                     // <= 11
        unsigned Mp = (1u << 20) / (unsigned)bwpq + 1;
        int totP = bhp * bwpq;                         // <= 484
        int x1p = x0p + bwp - 1;
#pragma unroll
        for (int ee = 0; ee < 2; ee++) {
            int e = tid + ee * 256;
            int valid = (e < totP) ? 1 : 0;
            int pr = (int)(((unsigned)e * Mp) >> 20);
            int pc = e - pr * bwpq;
            int sto = valid ? (pr * PSTR + pc * 4) : -1;
            if (ee == 0) psto0 = sto; else psto1 = sto;
            int py = y0p + pr;
            float Yg = (float)py + 0.5f;
            bool yok = (unsigned)py < (unsigned)Hn;
#pragma unroll
            for (int j = 0; j < 4; j++) {
                int px = min(x0p + pc * 4 + j, x1p);
                float Xg = (float)px + 0.5f;
                float r = __builtin_amdgcn_rcpf(g * Xg + h * Yg + 1.0f);
                float sx = (a0 * Xg + a1 * Yg + a2) * r - 0.5f;
                float sy = (a3 * Xg + a4 * Yg + a5) * r - 0.5f;
                float fx = floorf(sx), fy = floorf(sy);
                pwx[ee][j] = sx - fx;
                pwy[ee][j] = sy - fy;
                int off = ((int)fy - y0s) * FSTR + ((int)fx - x0s);
                off = min(max(off, 0), FH * FSTR - FSTR - 2);   // clamp (pad elems)
                bool inimg = yok && ((unsigned)px < (unsigned)Wn);
                poff[ee][j] = inimg ? off : (off | 0x40000000);
            }
        }
    }
    {
        float dxc = (float)(rx0 + oc) - cxc;
        float bx = cs * dxc + cxc;
        float by = -sn * dxc + cxc;
        bool cok = oc < nRx;
#pragma unroll
        for (int it = 0; it < 4; it++) {
            int rr = it * 8 + rbase;
            bool on = (rr < nTy) && cok;
            rsto[it] = on ? (rr * RSTR + oc) : -1;
            float dyr = (float)(ry0 + rr) - cxc;
            float srx = bx + sn * dyr;
            float sry = by + cs * dyr;
            float fx = floorf(srx), fy = floorf(sry);
            rwx[it] = srx - fx;
            rwy[it] = sry - fy;
            int off = ((int)fy - y0p) * PSTR + ((int)fx - x0p);
            roff[it] = min(max(off, 0), PHR * PSTR - PSTR - 2);
        }
    }
    {
        int ox = tx + oc;
        twt = g_wt[ox];
        int j0 = g_i0[ox];
        jc0 = min(max(j0 - 1, 0), CROPD - 1) - jmin;
        jc1 = min(max(j0 + 0, 0), CROPD - 1) - jmin;
        jc2 = min(max(j0 + 1, 0), CROPD - 1) - jmin;
        jc3 = min(max(j0 + 2, 0), CROPD - 1) - jmin;
    }
    {
        int r = tid >> 3, cg = tid & 7;
        int oy = ty + r;
        vwt = g_wt[oy];
        int i0y = g_i0[oy];
        iyc0 = (min(max(i0y - 1, 0), CROPD - 1) - iymin) * RSTR + cg * 4;
        iyc1 = (min(max(i0y + 0, 0), CROPD - 1) - iymin) * RSTR + cg * 4;
        iyc2 = (min(max(i0y + 1, 0), CROPD - 1) - iymin) * RSTR + cg * 4;
        iyc3 = (min(max(i0y + 2, 0), CROPD - 1) - iymin) * RSTR + cg * 4;
        voutoff = oy * Wn + tx + cg * 4;
    }

    // ============================ channel loop ==============================
    for (int c = 0; c < Cn; c++) {
        const size_t base = ((size_t)(b * Cn + c)) * (size_t)PLANE;
        const float* xb = xin + base;
        const float* nb = noise + base;

        if (fast) {
            // ---- F: zero-padded (flip(x)+0.625*noise)*bf ----
            for (int e = tid; e < totF; e += 256) {
                int fr = (int)(((unsigned)e * Mf) >> 20);
                int fc = e - fr * bwq;
                int yy = y0s + fr;
                int xl = x0s + fc * 4;
                bool yok = (unsigned)yy < (unsigned)Hn;
                float4 f;
                if (yok && xl >= 0 && xl <= Wn - 4) {
                    float4 nv = *reinterpret_cast<const float4*>(&nb[yy * Wn + xl]);
                    float4 xv;
                    if (flip) {
                        float4 xr = *reinterpret_cast<const float4*>(&xb[yy * Wn + (Wn - 4 - xl)]);
                        xv = make_float4(xr.w, xr.z, xr.y, xr.x);
                    } else {
                        xv = *reinterpret_cast<const float4*>(&xb[yy * Wn + xl]);
                    }
                    f = make_float4((xv.x + 0.625f * nv.x) * bf,
                                    (xv.y + 0.625f * nv.y) * bf,
                                    (xv.z + 0.625f * nv.z) * bf,
                                    (xv.w + 0.625f * nv.w) * bf);
                } else {
                    float v[4];
#pragma unroll
                    for (int j = 0; j < 4; j++) {
                        int xj = xl + j;
                        bool ok = yok && ((unsigned)xj < (unsigned)Wn);
                        int xcl = min(max(xj, 0), Wn - 1);
                        int xsl = flip ? (Wn - 1 - xcl) : xcl;
                        v[j] = ok ? (xb[yy * Wn + xsl] + 0.625f * nb[yy * Wn + xcl]) * bf
                                  : 0.f;
                    }
                    f = make_float4(v[0], v[1], v[2], v[3]);
                }
                *reinterpret_cast<float4*>(&Flds[fr * FSTR + fc * 4]) = f;
            }
            __syncthreads();

            // ---- P: cached coords -> zero-padded Plds ----
#pragma unroll
            for (int ee = 0; ee < 2; ee++) {
                int sto = (ee == 0) ? psto0 : psto1;
                if (sto >= 0) {
                    float pv[4];
#pragma unroll
                    for (int j = 0; j < 4; j++) {
                        int o = poff[ee][j];
                        const float* q = &Flds[o & 0x3fffffff];
                        float wx = pwx[ee][j], wy = pwy[ee][j];
                        float top = q[0] + wx * (q[1] - q[0]);
                        float bot = q[FSTR] + wx * (q[FSTR + 1] - q[FSTR]);
                        float v = top + wy * (bot - top);
                        pv[j] = (o & 0x40000000) ? 0.f : v;
                    }
                    *reinterpret_cast<float4*>(&Plds[sto]) =
                        make_float4(pv[0], pv[1], pv[2], pv[3]);
                }
            }
            __syncthreads();

            // ---- R: cached coords over zero-padded P ----
#pragma unroll
            for (int it = 0; it < 4; it++) {
                if (rsto[it] >= 0) {
                    const float* q = &Plds[roff[it]];
                    float wx = rwx[it], wy = rwy[it];
                    float top = q[0] + wx * (q[1] - q[0]);
                    float bot = q[PSTR] + wx * (q[PSTR + 1] - q[PSTR]);
                    Rlds[rsto[it]] = top + wy * (bot - top);
                }
            }
        } else {
            // ---- rare fallback: direct global-tap R ----
#pragma unroll
            for (int it = 0; it < 4; it++) {
                int rr = it * 8 + rbase;
                if (rr < nTy && oc < nRx) {
                    float dxc = (float)(rx0 + oc) - cxc;
                    float dyr = (float)(ry0 + rr) - cxc;
                    float srx = cs * dxc + sn * dyr + cxc;
                    float sry = -sn * dxc + cs * dyr + cxc;
                    float fx0 = floorf(srx), fy0 = floorf(sry);
                    float wx = srx - fx0, wy = sry - fy0;
                    int x0 = (int)fx0, y0 = (int)fy0;
                    float acc = 0.f;
#pragma unroll
                    for (int ddy = 0; ddy < 2; ddy++) {
                        int yy = y0 + ddy;
                        float wyv = ddy ? wy : 1.f - wy;
                        bool yv = (unsigned)yy < (unsigned)Hn;
                        int yc = min(max(yy, 0), Hn - 1);
#pragma unroll
                        for (int ddx = 0; ddx < 2; ddx++) {
                            int xx = x0 + ddx;
                            float wxv = ddx ? wx : 1.f - wx;
                            bool v = yv && ((unsigned)xx < (unsigned)Wn);
                            int xc = min(max(xx, 0), Wn - 1);
                            float wgt = v ? wxv * wyv : 0.f;
                            if (wgt != 0.f)
                                acc += persp_at(xb, nb, flip, bf, a0, a1, a2,
                                                a3, a4, a5, g, h, xc, yc) * wgt;
                        }
                    }
                    Rlds[rr * RSTR + oc] = acc;
                }
            }
        }
        __syncthreads();

        // ---- T: horizontal bicubic (cached coords) ----
#pragma unroll
        for (int it = 0; it < 4; it++) {
            int rr = it * 8 + rbase;
            if (rr < nTy) {
                const float* row = &Rlds[rr * RSTR];
                Tlds[rr * RSTR + oc] = twt.x * row[jc0] + twt.y * row[jc1] +
                                       twt.z * row[jc2] + twt.w * row[jc3];
            }
        }
        __syncthreads();

        // ---- V: vertical bicubic (cached coords), float4 store ----
        {
            float4 v0 = *reinterpret_cast<const float4*>(&Tlds[iyc0]);
            float4 v1 = *reinterpret_cast<const float4*>(&Tlds[iyc1]);
            float4 v2 = *reinterpret_cast<const float4*>(&Tlds[iyc2]);
            float4 v3 = *reinterpret_cast<const float4*>(&Tlds[iyc3]);
            float4 acc;
            acc.x = vwt.x * v0.x + vwt.y * v1.x + vwt.z * v2.x + vwt.w * v3.x;
            acc.y = vwt.x * v0.y + vwt.y * v1.y + vwt.z * v2.y + vwt.w * v3.y;
            acc.z = vwt.x * v0.z + vwt.y * v1.z + vwt.z * v2.z + vwt.w * v3.z;
            acc.w = vwt.x * v0.w + vwt.y * v1.w + vwt.z * v2.w + vwt.w * v3.w;
            *reinterpret_cast<float4*>(out + base + voutoff) = acc;
        }
        __syncthreads();   // R/T (overlaying F) must drain before next channel's F
    }
}

extern "C" void kernel_launch(void* const* d_in, const int* in_sizes, int n_in,
                              void* d_out, int out_size, void* d_ws, size_t ws_size,
                              hipStream_t stream) {
    const float* x          = (const float*)d_in[0];
    const float* noise      = (const float*)d_in[1];
    const float* brightness = (const float*)d_in[2];
    const int*   flip_mask  = (const int*)d_in[3];
    const int*   ep_raw     = (const int*)d_in[4];
    const int*   angles     = (const int*)d_in[5];
    const int*   crop_ij    = (const int*)d_in[6];
    float* out = (float*)d_out;

    float* params = (float*)d_ws;                              // 12 KB
    int4*  rmeta  = (int4*)((char*)d_ws + 16384);              // 12544*16
    int4*  smeta  = (int4*)((char*)d_ws + 16384 + 200704);

    params_kernel<<<1, 256, 0, stream>>>(ep_raw, angles, brightness, flip_mask, params);
    meta_kernel<<<49, 256, 0, stream>>>(params, crop_ij, rmeta, smeta);
    mega_kernel<<<NWG, 256, 0, stream>>>(x, noise, params, crop_ij, rmeta, smeta, out);
}

// Round 13
// 246.535 us; speedup vs baseline: 3.0165x; 3.0165x over previous
//
#include <hip/hip_runtime.h>
#include <math.h>

#define Bn 256
#define Cn 3
#define Hn 224
#define Wn 224
#define CROPD 190

static constexpr int PLANE = Hn * Wn;   // 50176

#define TILE 32
// F (source) tile: f32
#define FH 72
#define FSTR 76                  // floats
// P tile: f32
#define PHR 44
#define PSTR 48
// R/T tiles overlay F region
#define RSTR 40

#define NWG (768 * 49)     // 37,632
#define CHUNK (NWG / 8)

__device__ int    g_i0[Wn];
__device__ float4 g_wt[Wn];

__device__ __forceinline__ float keys_cubic(float x) {
    if (x < 1.f) return ((1.5f * x - 2.5f) * x) * x + 1.f;
    if (x < 2.f) return ((-0.5f * x + 2.5f) * x - 4.f) * x + 2.f;
    return 0.f;
}
__device__ __forceinline__ float rflf(float v) {
    return __int_as_float(__builtin_amdgcn_readfirstlane(__float_as_int(v)));
}
__device__ __forceinline__ int rfli(int v) { return __builtin_amdgcn_readfirstlane(v); }
__device__ __forceinline__ int swz_block(int bid) {
    return (bid & 7) * CHUNK + (bid >> 3);
}
__device__ __forceinline__ int i0_of(int o) {
    // identical float expression to the table fill — bit-identical results
    return (int)floorf(((float)o + 0.5f) * ((float)CROPD / (float)Wn) - 0.5f);
}

// Merged params + meta: 49 blocks x 256 = 12,544 threads, one per (batch,tile).
// Each thread redundantly solves its batch's 8x8 homography in f64 (parallel
// across blocks — replaces the serializing 1-block params dispatch), computes
// clamped bboxes + interior flags, writes params (t==0) and the bicubic table.
__global__ void meta_kernel(const int* __restrict__ ep_raw,
                            const int* __restrict__ angles,
                            const float* __restrict__ brightness,
                            const int* __restrict__ flip_mask,
                            const int* __restrict__ crop_ij,
                            float* __restrict__ params,
                            int4* __restrict__ rmeta,
                            int4* __restrict__ smeta) {
    int bt = blockIdx.x * 256 + threadIdx.x;    // < 12544 exactly
    int b = bt / 49, t = bt % 49;
    int ty = (t / 7) * TILE, tx = (t % 7) * TILE;

    // ---- bicubic weight table (first 224 threads of the grid) ----
    if (bt < Wn) {
        float sf = ((float)bt + 0.5f) * ((float)CROPD / (float)Wn) - 0.5f;
        int i0 = (int)floorf(sf);
        float w[4]; float s = 0.f;
#pragma unroll
        for (int k = 0; k < 4; k++) {
            int idx = i0 - 1 + k;
            float wk = (idx >= 0 && idx < CROPD) ? keys_cubic(fabsf(sf - (float)idx)) : 0.f;
            w[k] = wk; s += wk;
        }
        float inv = 1.f / s;
        g_i0[bt] = i0;
        g_wt[bt] = make_float4(w[0] * inv, w[1] * inv, w[2] * inv, w[3] * inv);
    }

    // ---- per-thread f64 homography solve (identical to old params_kernel) ----
    const double offx[4] = {0.0, 195.0, 195.0, 0.0};
    const double offy[4] = {0.0, 0.0, 195.0, 195.0};
    const double sxc[4]  = {0.0, 223.0, 223.0, 0.0};
    const double syc[4]  = {0.0, 0.0, 223.0, 223.0};
    double M[8][9];
    for (int i = 0; i < 4; i++) {
        double ex = (double)ep_raw[b * 8 + i * 2 + 0] + offx[i];
        double ey = (double)ep_raw[b * 8 + i * 2 + 1] + offy[i];
        double sx = sxc[i], sy = syc[i];
        M[i][0] = ex; M[i][1] = ey; M[i][2] = 1.0;
        M[i][3] = 0.0; M[i][4] = 0.0; M[i][5] = 0.0;
        M[i][6] = -sx * ex; M[i][7] = -sx * ey; M[i][8] = sx;
        M[i + 4][0] = 0.0; M[i + 4][1] = 0.0; M[i + 4][2] = 0.0;
        M[i + 4][3] = ex; M[i + 4][4] = ey; M[i + 4][5] = 1.0;
        M[i + 4][6] = -sy * ex; M[i + 4][7] = -sy * ey; M[i + 4][8] = sy;
    }
    for (int k = 0; k < 8; k++) {
        int piv = k; double best = fabs(M[k][k]);
        for (int r = k + 1; r < 8; r++) {
            double v = fabs(M[r][k]);
            if (v > best) { best = v; piv = r; }
        }
        if (piv != k)
            for (int j = 0; j < 9; j++) { double tt = M[k][j]; M[k][j] = M[piv][j]; M[piv][j] = tt; }
        double inv = 1.0 / M[k][k];
        for (int r = k + 1; r < 8; r++) {
            double f = M[r][k] * inv;
            M[r][k] = 0.0;
            for (int j = k + 1; j < 9; j++) M[r][j] -= f * M[k][j];
        }
    }
    double sol[8];
    for (int k = 7; k >= 0; k--) {
        double s = M[k][8];
        for (int j = k + 1; j < 8; j++) s -= M[k][j] * sol[j];
        sol[k] = s / M[k][k];
    }
    double th = ((double)angles[b] - 16.0) * (M_PI / 180.0);
    float a0 = (float)sol[0], a1 = (float)sol[1], a2 = (float)sol[2];
    float a3 = (float)sol[3], a4 = (float)sol[4], a5 = (float)sol[5];
    float g  = (float)sol[6], h  = (float)sol[7];
    float cs = (float)cos(th), sn = (float)sin(th);

    if (t == 0) {
        float* p = params + b * 12;
        p[0] = a0; p[1] = a1; p[2] = a2; p[3] = a3;
        p[4] = a4; p[5] = a5; p[6] = g;  p[7] = h;
        p[8]  = cs;
        p[9]  = sn;
        p[10] = 0.85f + 0.3f * brightness[b];
        p[11] = (flip_mask[b] > 0) ? 1.0f : 0.0f;
    }

    // ---- rot bbox over R rect -> clamped P-rect + interior flag ----
    int x0p, y0p, bwp, bhp;
    {
        int ci = crop_ij[b * 2 + 0], cj = crop_ij[b * 2 + 1];
        int iymin = max(i0_of(ty) - 1, 0);
        int iymax = min(i0_of(ty + 31) + 2, CROPD - 1);
        int jmin = max(i0_of(tx) - 1, 0);
        int jmax = min(i0_of(tx + 31) + 2, CROPD - 1);
        int ry0 = iymin + ci, ry1 = iymax + ci;
        int rx0 = jmin + cj, rx1 = jmax + cj;
        const float cxc = (Wn - 1) * 0.5f;
        float minrx = 1e30f, maxrx = -1e30f, minry = 1e30f, maxry = -1e30f;
#pragma unroll
        for (int cy = 0; cy < 2; cy++) {
#pragma unroll
            for (int cxr = 0; cxr < 2; cxr++) {
                float dx = (float)(cxr ? rx1 : rx0) - cxc;
                float dy = (float)(cy ? ry1 : ry0) - cxc;
                float rx = cs * dx + sn * dy + cxc;
                float ry = -sn * dx + cs * dy + cxc;
                minrx = fminf(minrx, rx); maxrx = fmaxf(maxrx, rx);
                minry = fminf(minry, ry); maxry = fmaxf(maxry, ry);
            }
        }
        int x0b = min(max((int)floorf(minrx) - 1, 0), Wn - 1);
        int x1b = min(max((int)floorf(maxrx) + 2, 0), Wn - 1);
        int y0b = min(max((int)floorf(minry) - 1, 0), Hn - 1);
        int y1b = min(max((int)floorf(maxry) + 2, 0), Hn - 1);
        x0p = x0b; y0p = y0b;
        bwp = x1b - x0b + 1; bhp = y1b - y0b + 1;
        int inter = (minrx >= 0.5f && maxrx <= 222.0f &&
                     minry >= 0.5f && maxry <= 222.0f) ? 1 : 0;
        rmeta[bt] = make_int4(x0b, y0b, bwp | (inter << 16), bhp);
    }

    // ---- persp source bbox over the P-rect ----
    {
        int x1p = x0p + bwp - 1, y1p = y0p + bhp - 1;
        float minsx = 1e30f, maxsx = -1e30f, minsy = 1e30f, maxsy = -1e30f;
#pragma unroll
        for (int cy = 0; cy < 2; cy++) {
#pragma unroll
            for (int cxr = 0; cxr < 2; cxr++) {
                float Xg = (float)(cxr ? x1p : x0p) + 0.5f;
                float Yg = (float)(cy ? y1p : y0p) + 0.5f;
                float rden = 1.0f / (g * Xg + h * Yg + 1.0f);
                float sx = (a0 * Xg + a1 * Yg + a2) * rden - 0.5f;
                float sy = (a3 * Xg + a4 * Yg + a5) * rden - 0.5f;
                minsx = fminf(minsx, sx); maxsx = fmaxf(maxsx, sx);
                minsy = fminf(minsy, sy); maxsy = fmaxf(maxsy, sy);
            }
        }
        int x0s = min(max((int)floorf(minsx) - 1, 0), Wn - 1);
        int x1s = min(max((int)floorf(maxsx) + 2, 0), Wn - 1);
        int y0s = min(max((int)floorf(minsy) - 1, 0), Hn - 1);
        int y1s = min(max((int)floorf(maxsy) + 2, 0), Hn - 1);
        x0s &= ~3;
        int bws = x1s - x0s + 1, bhs = y1s - y0s + 1;
        int inter = (minsx >= 0.5f && maxsx <= 222.0f &&
                     minsy >= 0.5f && maxsy <= 222.0f) ? 1 : 0;
        smeta[bt] = make_int4(x0s, y0s, bws | (inter << 16), bhs);
    }
}

// On-demand perspective sample with global taps (ultra-rare fallback path).
__device__ __forceinline__ float persp_at(const float* __restrict__ xb,
                                          const float* __restrict__ nb,
                                          bool flip, float bf,
                                          float a0, float a1, float a2,
                                          float a3, float a4, float a5,
                                          float g, float h, int ixp, int iyp) {
    float Xg = (float)ixp + 0.5f, Yg = (float)iyp + 0.5f;
    float rden = __builtin_amdgcn_rcpf(g * Xg + h * Yg + 1.0f);
    float sx = (a0 * Xg + a1 * Yg + a2) * rden - 0.5f;
    float sy = (a3 * Xg + a4 * Yg + a5) * rden - 0.5f;
    float fx0 = floorf(sx), fy0 = floorf(sy);
    float wx = sx - fx0, wy = sy - fy0;
    int x0 = (int)fx0, y0 = (int)fy0;
    float acc = 0.f;
#pragma unroll
    for (int dy = 0; dy < 2; dy++) {
        int yy = y0 + dy;
        float wyv = dy ? wy : 1.f - wy;
        bool yv = (unsigned)yy < (unsigned)Hn;
        int yc = min(max(yy, 0), Hn - 1);
#pragma unroll
        for (int dx = 0; dx < 2; dx++) {
            int xx = x0 + dx;
            float wxv = dx ? wx : 1.f - wx;
            bool v = yv && ((unsigned)xx < (unsigned)Wn);
            int xc = min(max(xx, 0), Wn - 1);
            float wgt = v ? wxv * wyv : 0.f;
            int xs = flip ? (Wn - 1 - xc) : xc;
            acc += (xb[yc * Wn + xs] + 0.625f * nb[yc * Wn + xc]) * bf * wgt;
        }
    }
    return acc;
}

// Fully fused pipeline — R8 structure VERBATIM (best measured: 235 us).
// F and P both f32; R/T overlay dead F. LDS = 30,336 B -> 5 blocks/CU.
__global__ __launch_bounds__(256, 5) void mega_kernel(const float* __restrict__ xin,
                                                      const float* __restrict__ noise,
                                                      const float* __restrict__ params,
                                                      const int* __restrict__ crop_ij,
                                                      const int4* __restrict__ rmeta,
                                                      const int4* __restrict__ smeta,
                                                      float* __restrict__ out) {
    __shared__ __align__(16) float smem[FH * FSTR + PHR * PSTR];
    float* Flds = smem;
    float* Plds = smem + FH * FSTR;
    float* Rlds = smem;                      // overlays F (dead after P phase)
    float* Tlds = smem + 32 * RSTR;

    int bi = swz_block(blockIdx.x);
    int p = bi / 49;
    int t = bi % 49;
    int ty = (t / 7) * TILE;
    int tx = (t % 7) * TILE;
    int b = p / Cn;
    int tid = threadIdx.x;

    int4 rm = rmeta[b * 49 + t];
    int x0p = rm.x, y0p = rm.y;
    int bwp = rm.z & 0xffff;
    bool interior_r = (rm.z >> 16) != 0;
    int bhp = rm.w;
    int4 sm = smeta[b * 49 + t];
    int x0s = sm.x, y0s = sm.y;
    int bws = sm.z & 0xffff;
    bool interior_s = (sm.z >> 16) != 0;
    int bhs = sm.w;
    bool fitF = (bws <= FH) && (bhs <= FH);
    bool fitP = (bwp <= PHR) && (bhp <= PHR);
    bool fast = fitF && fitP;

    const float* prm = params + b * 12;
    float a0 = rflf(prm[0]), a1 = rflf(prm[1]), a2 = rflf(prm[2]);
    float a3 = rflf(prm[3]), a4 = rflf(prm[4]), a5 = rflf(prm[5]);
    float g = rflf(prm[6]), h = rflf(prm[7]), bf = rflf(prm[10]);
    float cs = rflf(prm[8]), sn = rflf(prm[9]);
    bool flip = rflf(prm[11]) > 0.5f;
    int ci = rfli(crop_ij[b * 2 + 0]);
    int cj = rfli(crop_ij[b * 2 + 1]);

    int iymin = max(g_i0[ty] - 1, 0);
    int nTy = min(g_i0[ty + 31] + 2, CROPD - 1) - iymin + 1;
    int jmin = max(g_i0[tx] - 1, 0);
    int nRx = min(g_i0[tx + 31] + 2, CROPD - 1) - jmin + 1;
    int rx0 = jmin + cj, ry0 = iymin + ci;
    const float cxc = (Wn - 1) * 0.5f;

    const size_t base = (size_t)p * PLANE;
    const float* xb = xin + base;
    const float* nb = noise + base;

    // ---- Phase F: stage (flip(x)+0.625*noise)*bf, f32, linear magic-div map ----
    if (fast) {
        int bwq = (bws + 3) >> 2;                     // quads/row, <= 18
        unsigned Mf = (1u << 20) / (unsigned)bwq + 1;
        int totF = bhs * bwq;                         // <= 1296
        for (int e = tid; e < totF; e += 256) {
            int fr = (int)(((unsigned)e * Mf) >> 20);
            int fc = e - fr * bwq;
            int yy = y0s + fr;
            int xl = min(x0s + fc * 4, Wn - 4);       // 4-aligned
            float4 nv = *reinterpret_cast<const float4*>(&nb[yy * Wn + xl]);
            float4 xv;
            if (flip) {
                float4 xr = *reinterpret_cast<const float4*>(&xb[yy * Wn + (Wn - 4 - xl)]);
                xv = make_float4(xr.w, xr.z, xr.y, xr.x);
            } else {
                xv = *reinterpret_cast<const float4*>(&xb[yy * Wn + xl]);
            }
            float4 f = make_float4((xv.x + 0.625f * nv.x) * bf,
                                   (xv.y + 0.625f * nv.y) * bf,
                                   (xv.z + 0.625f * nv.z) * bf,
                                   (xv.w + 0.625f * nv.w) * bf);
            *reinterpret_cast<float4*>(&Flds[fr * FSTR + (xl - x0s)]) = f;
        }
    }
    __syncthreads();

    // ---- Phase P: perspective bilinear -> Plds, linear magic-div map ----
    if (fast) {
        int bwpq = (bwp + 3) >> 2;                     // <= 11
        unsigned Mp = (1u << 20) / (unsigned)bwpq + 1;
        int totP = bhp * bwpq;
        if (interior_s) {
            for (int e = tid; e < totP; e += 256) {
                int pr = (int)(((unsigned)e * Mp) >> 20);
                int pc = e - pr * bwpq;
                float Yg = (float)(y0p + pr) + 0.5f;
                float Xg0 = (float)(x0p + pc * 4) + 0.5f;
                float nx = a0 * Xg0 + (a1 * Yg + a2);
                float ny = a3 * Xg0 + (a4 * Yg + a5);
                float dn = g * Xg0 + (h * Yg + 1.0f);
                float pv[4];
#pragma unroll
                for (int j = 0; j < 4; j++) {
                    float r = __builtin_amdgcn_rcpf(dn);
                    float sx = nx * r - 0.5f;          // > 0 (interior)
                    float sy = ny * r - 0.5f;
                    int ix = (int)sx; float wx = sx - (float)ix;
                    int iy = (int)sy; float wy = sy - (float)iy;
                    const float* q = &Flds[(iy - y0s) * FSTR + (ix - x0s)];
                    float top = q[0] + wx * (q[1] - q[0]);
                    float bot = q[FSTR] + wx * (q[FSTR + 1] - q[FSTR]);
                    pv[j] = top + wy * (bot - top);
                    nx += a0; ny += a3; dn += g;
                }
                *reinterpret_cast<float4*>(&Plds[pr * PSTR + pc * 4]) =
                    make_float4(pv[0], pv[1], pv[2], pv[3]);
            }
        } else {
            for (int e = tid; e < totP; e += 256) {
                int pr = (int)(((unsigned)e * Mp) >> 20);
                int pc = e - pr * bwpq;
                float Yg = (float)(y0p + pr) + 0.5f;
                float Xg0 = (float)(x0p + pc * 4) + 0.5f;
                float nx = a0 * Xg0 + (a1 * Yg + a2);
                float ny = a3 * Xg0 + (a4 * Yg + a5);
                float dn = g * Xg0 + (h * Yg + 1.0f);
                float pv[4];
#pragma unroll
                for (int j = 0; j < 4; j++) {
                    float r = __builtin_amdgcn_rcpf(dn);
                    float sx = nx * r - 0.5f;
                    float sy = ny * r - 0.5f;
                    float fx0 = floorf(sx), fy0 = floorf(sy);
                    float wx = sx - fx0, wy = sy - fy0;
                    int x0 = (int)fx0, y0 = (int)fy0;
                    float acc = 0.f;
#pragma unroll
                    for (int dy = 0; dy < 2; dy++) {
                        int yy = y0 + dy;
                        float wyv = dy ? wy : 1.f - wy;
                        bool yv = (unsigned)yy < (unsigned)Hn;
                        int yc = min(max(yy, 0), Hn - 1);
#pragma unroll
                        for (int dx = 0; dx < 2; dx++) {
                            int xx = x0 + dx;
                            float wxv = dx ? wx : 1.f - wx;
                            bool v = yv && ((unsigned)xx < (unsigned)Wn);
                            int xc = min(max(xx, 0), Wn - 1);
                            float wgt = v ? wxv * wyv : 0.f;
                            acc += Flds[(yc - y0s) * FSTR + (xc - x0s)] * wgt;
                        }
                    }
                    pv[j] = acc;
                    nx += a0; ny += a3; dn += g;
                }
                *reinterpret_cast<float4*>(&Plds[pr * PSTR + pc * 4]) =
                    make_float4(pv[0], pv[1], pv[2], pv[3]);
            }
        }
    }
    __syncthreads();

    // ---- Phase R: rotation bilinear (P taps) -> Rlds ----
    {
        int rc = tid & 31;
        int rbase = tid >> 5;
        bool cok = rc < nRx;
        float dxc = (float)(rx0 + rc) - cxc;
        float bx = cs * dxc + cxc;
        float by = -sn * dxc + cxc;
        if (fast && interior_r) {
#pragma unroll
            for (int it = 0; it < 4; it++) {
                int rr = it * 8 + rbase;
                if (rr < nTy && cok) {
                    float dyr = (float)(ry0 + rr) - cxc;
                    float srx = bx + sn * dyr;         // > 0 (interior)
                    float sry = by + cs * dyr;
                    int ix = (int)srx; float wx = srx - (float)ix;
                    int iy = (int)sry; float wy = sry - (float)iy;
                    const float* q = &Plds[(iy - y0p) * PSTR + (ix - x0p)];
                    float top = q[0] + wx * (q[1] - q[0]);
                    float bot = q[PSTR] + wx * (q[PSTR + 1] - q[PSTR]);
                    Rlds[rr * RSTR + rc] = top + wy * (bot - top);
                }
            }
        } else if (fast) {
#pragma unroll
            for (int it = 0; it < 4; it++) {
                int rr = it * 8 + rbase;
                if (rr < nTy && cok) {
                    float dyr = (float)(ry0 + rr) - cxc;
                    float srx = bx + sn * dyr;
                    float sry = by + cs * dyr;
                    float fx0 = floorf(srx), fy0 = floorf(sry);
                    float wx = srx - fx0, wy = sry - fy0;
                    int x0 = (int)fx0, y0 = (int)fy0;
                    float acc = 0.f;
#pragma unroll
                    for (int ddy = 0; ddy < 2; ddy++) {
                        int yy = y0 + ddy;
                        float wyv = ddy ? wy : 1.f - wy;
                        bool yv = (unsigned)yy < (unsigned)Hn;
                        int yc = min(max(yy, 0), Hn - 1);
#pragma unroll
                        for (int ddx = 0; ddx < 2; ddx++) {
                            int xx = x0 + ddx;
                            float wxv = ddx ? wx : 1.f - wx;
                            bool v = yv && ((unsigned)xx < (unsigned)Wn);
                            int xc = min(max(xx, 0), Wn - 1);
                            float wgt = v ? wxv * wyv : 0.f;
                            acc += Plds[(yc - y0p) * PSTR + (xc - x0p)] * wgt;
                        }
                    }
                    Rlds[rr * RSTR + rc] = acc;
                }
            }
        } else {
#pragma unroll
            for (int it = 0; it < 4; it++) {
                int rr = it * 8 + rbase;
                if (rr < nTy && cok) {
                    float dyr = (float)(ry0 + rr) - cxc;
                    float srx = bx + sn * dyr;
                    float sry = by + cs * dyr;
                    float fx0 = floorf(srx), fy0 = floorf(sry);
                    float wx = srx - fx0, wy = sry - fy0;
                    int x0 = (int)fx0, y0 = (int)fy0;
                    float acc = 0.f;
#pragma unroll
                    for (int ddy = 0; ddy < 2; ddy++) {
                        int yy = y0 + ddy;
                        float wyv = ddy ? wy : 1.f - wy;
                        bool yv = (unsigned)yy < (unsigned)Hn;
                        int yc = min(max(yy, 0), Hn - 1);
#pragma unroll
                        for (int ddx = 0; ddx < 2; ddx++) {
                            int xx = x0 + ddx;
                            float wxv = ddx ? wx : 1.f - wx;
                            bool v = yv && ((unsigned)xx < (unsigned)Wn);
                            int xc = min(max(xx, 0), Wn - 1);
                            float wgt = v ? wxv * wyv : 0.f;
                            if (wgt != 0.f)
                                acc += persp_at(xb, nb, flip, bf, a0, a1, a2,
                                                a3, a4, a5, g, h, xc, yc) * wgt;
                        }
                    }
                    Rlds[rr * RSTR + rc] = acc;
                }
            }
        }
    }
    __syncthreads();

    // ---- Phase T: horizontal bicubic ----
    {
        int oc = tid & 31;
        int rbase = tid >> 5;
        int ox = tx + oc;
        float4 w = g_wt[ox];
        int j0 = g_i0[ox];
        int jc0 = min(max(j0 - 1, 0), CROPD - 1) - jmin;
        int jc1 = min(max(j0 + 0, 0), CROPD - 1) - jmin;
        int jc2 = min(max(j0 + 1, 0), CROPD - 1) - jmin;
        int jc3 = min(max(j0 + 2, 0), CROPD - 1) - jmin;
#pragma unroll
        for (int it = 0; it < 4; it++) {
            int rr = it * 8 + rbase;
            if (rr < nTy) {
                const float* row = &Rlds[rr * RSTR];
                Tlds[rr * RSTR + oc] = w.x * row[jc0] + w.y * row[jc1] +
                                       w.z * row[jc2] + w.w * row[jc3];
            }
        }
    }
    __syncthreads();

    // ---- Phase V: vertical bicubic, float4 store ----
    {
        int r = tid >> 3, cg = tid & 7;
        int oy = ty + r, ox0 = tx + cg * 4;
        float4 w = g_wt[oy];
        int i0y = g_i0[oy];
        float wk[4] = {w.x, w.y, w.z, w.w};
        float4 acc = make_float4(0.f, 0.f, 0.f, 0.f);
#pragma unroll
        for (int k = 0; k < 4; k++) {
            int iyc = min(max(i0y - 1 + k, 0), CROPD - 1) - iymin;
            float4 v = *reinterpret_cast<const float4*>(&Tlds[iyc * RSTR + cg * 4]);
            acc.x += wk[k] * v.x;
            acc.y += wk[k] * v.y;
            acc.z += wk[k] * v.z;
            acc.w += wk[k] * v.w;
        }
        *reinterpret_cast<float4*>(out + base + (size_t)oy * Wn + ox0) = acc;
    }
}

extern "C" void kernel_launch(void* const* d_in, const int* in_sizes, int n_in,
                              void* d_out, int out_size, void* d_ws, size_t ws_size,
                              hipStream_t stream) {
    const float* x          = (const float*)d_in[0];
    const float* noise      = (const float*)d_in[1];
    const float* brightness = (const float*)d_in[2];
    const int*   flip_mask  = (const int*)d_in[3];
    const int*   ep_raw     = (const int*)d_in[4];
    const int*   angles     = (const int*)d_in[5];
    const int*   crop_ij    = (const int*)d_in[6];
    float* out = (float*)d_out;

    float* params = (float*)d_ws;                              // 12 KB
    int4*  rmeta  = (int4*)((char*)d_ws + 16384);              // 12544*16
    int4*  smeta  = (int4*)((char*)d_ws + 16384 + 200704);

    meta_kernel<<<49, 256, 0, stream>>>(ep_raw, angles, brightness, flip_mask,
                                        crop_ij, params, rmeta, smeta);
    mega_kernel<<<NWG, 256, 0, stream>>>(x, noise, params, crop_ij, rmeta, smeta, out);
}